// Round 3
// baseline (356.544 us; speedup 1.0000x reference)
//
#include <hip/hip_runtime.h>
#include <hip/hip_bf16.h>

#define V_SIZE 32000
#define SEQ 64
#define BATCH 64
#define EMB 32
#define HID 16
#define NROWS (SEQ * BATCH)   // 4096
#define V4 (V_SIZE / 4)       // 8000 float4 columns
#define ROWS_B 4
#define ROWS_C 4

// ---------------------------------------------------------------------------
// Kernel A: h_table[r][j] = sigmoid( lookup[idx[r]] . wx[:,j] + (h0 @ wh)[j] )
// 4096 rows, one thread per row. Tiny.
// ---------------------------------------------------------------------------
__global__ __launch_bounds__(256) void k_htable(
    const int* __restrict__ idx, const float* __restrict__ lookup,
    const float* __restrict__ wx, const float* __restrict__ wh,
    const float* __restrict__ h0, float* __restrict__ h_table)
{
    int r = blockIdx.x * 256 + threadIdx.x;
    if (r >= NROWS) return;

    float acc[HID];
    #pragma unroll
    for (int j = 0; j < HID; ++j) acc[j] = 0.f;

    // h_rec = h0 @ wh  (redundant per thread; 256 FMA, negligible)
    #pragma unroll
    for (int i = 0; i < HID; ++i) {
        float h0i = h0[i];
        #pragma unroll
        for (int j = 0; j < HID; ++j) acc[j] += h0i * wh[i * HID + j];
    }

    int tok = idx[r];
    const float* xrow = lookup + (long)tok * EMB;
    #pragma unroll
    for (int e = 0; e < EMB; ++e) {
        float x = xrow[e];
        #pragma unroll
        for (int j = 0; j < HID; ++j) acc[j] += x * wx[e * HID + j];
    }

    #pragma unroll
    for (int j = 0; j < HID; ++j) {
        // sigmoid
        h_table[r * HID + j] = 1.f / (1.f + __expf(-acc[j]));
    }
}

// ---------------------------------------------------------------------------
// Kernel B: lse[r] = log( sum_v exp( h[r] . wo[:,v] ) )
// |logit| <= 4 (h in (0,1), |wo| <= 0.25, K=16) -> no max subtraction needed.
// 4 rows per block, 256 threads, float4 over V.
// ---------------------------------------------------------------------------
__global__ __launch_bounds__(256) void k_lse(
    const float* __restrict__ h_table, const float* __restrict__ wo,
    float* __restrict__ lse)
{
    const int tid = threadIdx.x;
    const int r0 = blockIdx.x * ROWS_B;

    float h[ROWS_B][HID];
    #pragma unroll
    for (int r = 0; r < ROWS_B; ++r)
        #pragma unroll
        for (int j = 0; j < HID; ++j)
            h[r][j] = h_table[(r0 + r) * HID + j];

    float acc[ROWS_B] = {0.f, 0.f, 0.f, 0.f};
    const float4* wo4 = reinterpret_cast<const float4*>(wo);

    for (int v4 = tid; v4 < V4; v4 += 256) {
        float4 w[HID];
        #pragma unroll
        for (int j = 0; j < HID; ++j) w[j] = wo4[j * V4 + v4];

        #pragma unroll
        for (int r = 0; r < ROWS_B; ++r) {
            float l0 = 0.f, l1 = 0.f, l2 = 0.f, l3 = 0.f;
            #pragma unroll
            for (int j = 0; j < HID; ++j) {
                l0 += h[r][j] * w[j].x;
                l1 += h[r][j] * w[j].y;
                l2 += h[r][j] * w[j].z;
                l3 += h[r][j] * w[j].w;
            }
            acc[r] += __expf(l0) + __expf(l1) + __expf(l2) + __expf(l3);
        }
    }

    // 64-lane butterfly reduce per row
    #pragma unroll
    for (int off = 32; off >= 1; off >>= 1) {
        #pragma unroll
        for (int r = 0; r < ROWS_B; ++r)
            acc[r] += __shfl_xor(acc[r], off, 64);
    }

    __shared__ float part[4][ROWS_B];
    const int wave = tid >> 6;
    const int lane = tid & 63;
    if (lane == 0) {
        #pragma unroll
        for (int r = 0; r < ROWS_B; ++r) part[wave][r] = acc[r];
    }
    __syncthreads();
    if (tid < ROWS_B) {
        float s = part[0][tid] + part[1][tid] + part[2][tid] + part[3][tid];
        lse[r0 + tid] = __logf(s);
    }
}

// ---------------------------------------------------------------------------
// Kernel C: out[r][v] = h[r] . wo[:,v] - lse[r]   (recompute logits, 1x write)
// ---------------------------------------------------------------------------
__global__ __launch_bounds__(256) void k_write(
    const float* __restrict__ h_table, const float* __restrict__ wo,
    const float* __restrict__ lse, float* __restrict__ out)
{
    const int tid = threadIdx.x;
    const int r0 = blockIdx.x * ROWS_C;

    float h[ROWS_C][HID];
    float ls[ROWS_C];
    #pragma unroll
    for (int r = 0; r < ROWS_C; ++r) {
        ls[r] = lse[r0 + r];
        #pragma unroll
        for (int j = 0; j < HID; ++j)
            h[r][j] = h_table[(r0 + r) * HID + j];
    }

    const float4* wo4 = reinterpret_cast<const float4*>(wo);
    float4* out4 = reinterpret_cast<float4*>(out);

    for (int v4 = tid; v4 < V4; v4 += 256) {
        float4 w[HID];
        #pragma unroll
        for (int j = 0; j < HID; ++j) w[j] = wo4[j * V4 + v4];

        #pragma unroll
        for (int r = 0; r < ROWS_C; ++r) {
            float l0 = 0.f, l1 = 0.f, l2 = 0.f, l3 = 0.f;
            #pragma unroll
            for (int j = 0; j < HID; ++j) {
                l0 += h[r][j] * w[j].x;
                l1 += h[r][j] * w[j].y;
                l2 += h[r][j] * w[j].z;
                l3 += h[r][j] * w[j].w;
            }
            float4 o;
            o.x = l0 - ls[r];
            o.y = l1 - ls[r];
            o.z = l2 - ls[r];
            o.w = l3 - ls[r];
            out4[(long)(r0 + r) * V4 + v4] = o;
        }
    }
}

extern "C" void kernel_launch(void* const* d_in, const int* in_sizes, int n_in,
                              void* d_out, int out_size, void* d_ws, size_t ws_size,
                              hipStream_t stream) {
    const int*   idx    = (const int*)d_in[0];
    const float* lookup = (const float*)d_in[1];
    const float* wx     = (const float*)d_in[2];
    const float* wh     = (const float*)d_in[3];
    const float* wo     = (const float*)d_in[4];
    const float* h0     = (const float*)d_in[5];
    float* out = (float*)d_out;

    float* h_table = (float*)d_ws;                 // 4096*16 floats = 256 KB
    float* lse     = h_table + NROWS * HID;        // 4096 floats

    k_htable<<<NROWS / 256, 256, 0, stream>>>(idx, lookup, wx, wh, h0, h_table);
    k_lse<<<NROWS / ROWS_B, 256, 0, stream>>>(h_table, wo, lse);
    k_write<<<NROWS / ROWS_C, 256, 0, stream>>>(h_table, wo, lse, out);
}

// Round 5
// 282.925 us; speedup vs baseline: 1.2602x; 1.2602x over previous
//
#include <hip/hip_runtime.h>
#include <hip/hip_bf16.h>

#define V_SIZE 32000
#define SEQ 64
#define BATCH 64
#define EMB 32
#define HID 16
#define NROWS (SEQ * BATCH)   // 4096
#define V4 (V_SIZE / 4)       // 8000 float4 columns
#define ROWS_B 8              // rows per k_lse block
#define ROWS_W 128            // rows per k_write block
#define STRIPS 32             // 32 strips * 256 f4-cols = 8192 >= 8000

typedef float f32x4 __attribute__((ext_vector_type(4)));

// ---------------------------------------------------------------------------
// Kernel A: h_table[r][j] = sigmoid( lookup[idx[r]] . wx[:,j] + (h0 @ wh)[j] )
// ---------------------------------------------------------------------------
__global__ __launch_bounds__(256) void k_htable(
    const int* __restrict__ idx, const float* __restrict__ lookup,
    const float* __restrict__ wx, const float* __restrict__ wh,
    const float* __restrict__ h0, float* __restrict__ h_table)
{
    int r = blockIdx.x * 256 + threadIdx.x;
    if (r >= NROWS) return;

    float acc[HID];
    #pragma unroll
    for (int j = 0; j < HID; ++j) acc[j] = 0.f;

    #pragma unroll
    for (int i = 0; i < HID; ++i) {
        float h0i = h0[i];
        #pragma unroll
        for (int j = 0; j < HID; ++j) acc[j] += h0i * wh[i * HID + j];
    }

    int tok = idx[r];
    const float* xrow = lookup + (long)tok * EMB;
    #pragma unroll
    for (int e = 0; e < EMB; ++e) {
        float x = xrow[e];
        #pragma unroll
        for (int j = 0; j < HID; ++j) acc[j] += x * wx[e * HID + j];
    }

    #pragma unroll
    for (int j = 0; j < HID; ++j)
        h_table[r * HID + j] = 1.f / (1.f + __expf(-acc[j]));
}

// ---------------------------------------------------------------------------
// Kernel B: lse[r] = log( sum_v exp( h[r] . wo[:,v] ) )
// |logit| <= 4 -> no max subtraction. 8 rows/block, full V sweep per block.
// L2 traffic: 512 blocks x 2 MB = 1 GB.
// ---------------------------------------------------------------------------
__global__ __launch_bounds__(256, 2) void k_lse(
    const float* __restrict__ h_table, const float* __restrict__ wo,
    float* __restrict__ lse)
{
    const int tid = threadIdx.x;
    const int r0 = blockIdx.x * ROWS_B;

    float h[ROWS_B][HID];
    #pragma unroll
    for (int r = 0; r < ROWS_B; ++r)
        #pragma unroll
        for (int j = 0; j < HID; ++j)
            h[r][j] = h_table[(r0 + r) * HID + j];

    float acc[ROWS_B];
    #pragma unroll
    for (int r = 0; r < ROWS_B; ++r) acc[r] = 0.f;

    const f32x4* wo4 = reinterpret_cast<const f32x4*>(wo);

    for (int v4 = tid; v4 < V4; v4 += 256) {
        f32x4 w[HID];
        #pragma unroll
        for (int j = 0; j < HID; ++j) w[j] = wo4[j * V4 + v4];

        #pragma unroll
        for (int r = 0; r < ROWS_B; ++r) {
            float l0 = 0.f, l1 = 0.f, l2 = 0.f, l3 = 0.f;
            #pragma unroll
            for (int j = 0; j < HID; ++j) {
                l0 += h[r][j] * w[j].x;
                l1 += h[r][j] * w[j].y;
                l2 += h[r][j] * w[j].z;
                l3 += h[r][j] * w[j].w;
            }
            acc[r] += __expf(l0) + __expf(l1) + __expf(l2) + __expf(l3);
        }
    }

    // 64-lane butterfly reduce per row
    #pragma unroll
    for (int off = 32; off >= 1; off >>= 1) {
        #pragma unroll
        for (int r = 0; r < ROWS_B; ++r)
            acc[r] += __shfl_xor(acc[r], off, 64);
    }

    __shared__ float part[4][ROWS_B];
    const int wave = tid >> 6;
    const int lane = tid & 63;
    if (lane == 0) {
        #pragma unroll
        for (int r = 0; r < ROWS_B; ++r) part[wave][r] = acc[r];
    }
    __syncthreads();
    if (tid < ROWS_B) {
        float s = part[0][tid] + part[1][tid] + part[2][tid] + part[3][tid];
        lse[r0 + tid] = __logf(s);
    }
}

// ---------------------------------------------------------------------------
// Kernel C (flipped): thread owns ONE float4 column-group; its 16 Wo float4s
// live in registers across 128 rows. h/lse arrive as wave-uniform scalar
// loads (SGPR). Nontemporal stores keep the 524 MB stream out of L2.
// Wo L2 traffic: 32 row-chunks x 2 MB = 64 MB total.
// ---------------------------------------------------------------------------
__global__ __launch_bounds__(256) void k_write(
    const float* __restrict__ h_table, const float* __restrict__ wo,
    const float* __restrict__ lse, float* __restrict__ out)
{
    const int tid = threadIdx.x;
    const int strip = blockIdx.x & (STRIPS - 1);
    const int chunk = blockIdx.x / STRIPS;
    const int v4 = strip * 256 + tid;
    const bool act = v4 < V4;
    const int r0 = chunk * ROWS_W;

    const f32x4* wo4 = reinterpret_cast<const f32x4*>(wo);
    f32x4 w[HID];
    #pragma unroll
    for (int j = 0; j < HID; ++j) {
        if (act) w[j] = wo4[j * V4 + v4];
        else     w[j] = (f32x4){0.f, 0.f, 0.f, 0.f};
    }

    f32x4* out4 = reinterpret_cast<f32x4*>(out);

    for (int r = r0; r < r0 + ROWS_W; ++r) {
        const float* h = h_table + r * HID;   // wave-uniform -> s_load
        const float ls = lse[r];              // wave-uniform -> s_load

        float l0 = 0.f, l1 = 0.f, l2 = 0.f, l3 = 0.f;
        #pragma unroll
        for (int j = 0; j < HID; ++j) {
            float hj = h[j];
            l0 += hj * w[j].x;
            l1 += hj * w[j].y;
            l2 += hj * w[j].z;
            l3 += hj * w[j].w;
        }
        if (act) {
            f32x4 o;
            o.x = l0 - ls; o.y = l1 - ls; o.z = l2 - ls; o.w = l3 - ls;
            __builtin_nontemporal_store(o, &out4[(long)r * V4 + v4]);
        }
    }
}

extern "C" void kernel_launch(void* const* d_in, const int* in_sizes, int n_in,
                              void* d_out, int out_size, void* d_ws, size_t ws_size,
                              hipStream_t stream) {
    const int*   idx    = (const int*)d_in[0];
    const float* lookup = (const float*)d_in[1];
    const float* wx     = (const float*)d_in[2];
    const float* wh     = (const float*)d_in[3];
    const float* wo     = (const float*)d_in[4];
    const float* h0     = (const float*)d_in[5];
    float* out = (float*)d_out;

    float* h_table = (float*)d_ws;                 // 4096*16 floats = 256 KB
    float* lse     = h_table + NROWS * HID;        // 4096 floats

    k_htable<<<NROWS / 256, 256, 0, stream>>>(idx, lookup, wx, wh, h0, h_table);
    k_lse<<<NROWS / ROWS_B, 256, 0, stream>>>(h_table, wo, lse);
    k_write<<<STRIPS * (NROWS / ROWS_W), 256, 0, stream>>>(h_table, wo, lse, out);
}